// Round 1
// baseline (746.752 us; speedup 1.0000x reference)
//
#include <hip/hip_runtime.h>

typedef __bf16 bf16;
typedef bf16 bf16x4 __attribute__((ext_vector_type(4)));
typedef bf16 bf16x8 __attribute__((ext_vector_type(8)));
typedef float floatx4 __attribute__((ext_vector_type(4)));

#define MFMA(a, b, c) __builtin_amdgcn_mfma_f32_16x16x32_bf16((a), (b), (c), 0, 0, 0)

__device__ __forceinline__ void gl2lds16(const void* g, void* l) {
  __builtin_amdgcn_global_load_lds(
      (const __attribute__((address_space(1))) void*)g,
      (__attribute__((address_space(3))) void*)l, 16, 0, 0);
}

__device__ __forceinline__ bf16x4 cvt4(const float4 v) {
  bf16x4 o;
  o[0] = (bf16)v.x; o[1] = (bf16)v.y; o[2] = (bf16)v.z; o[3] = (bf16)v.w;
  return o;
}

// ---------------- Kernel 1: W fp32 -> bf16 ----------------
__global__ __launch_bounds__(256) void cast_w_kernel(const float* __restrict__ W,
                                                     bf16* __restrict__ Wb, int n4) {
  int idx = blockIdx.x * 256 + threadIdx.x;
  int stride = gridDim.x * 256;
  const float4* W4 = (const float4*)W;
  for (int i = idx; i < n4; i += stride) {
    *(bf16x4*)(Wb + (size_t)i * 4) = cvt4(W4[i]);
  }
}

// ---------------- Kernel 2: block-diagonal MLP (both einsums + biases + ReLUs) ----
// grid: (rows/128 batch-tiles, 64 r). 256 threads = 4 waves.
// GEMM1: C1[b',m] = sum_k X[b',k]*P1[m,k]   (K=64)   -> ReLU -> H1 (bf16, LDS)
// GEMM2: C2[b',kk] = sum_m H1[b',m]*P2[kk,m] (K=256, processed in 4 quarters)
__global__ __launch_bounds__(256) void blockdiag_kernel(
    const float* __restrict__ x, const float* __restrict__ p1,
    const float* __restrict__ b1, const float* __restrict__ p2,
    const float* __restrict__ b2, bf16* __restrict__ h2) {
  __shared__ bf16 sX[128 * 72];   // [128 rows][64 k] pad->72
  __shared__ bf16 sP1[64 * 72];   // [64 m (quarter)][64 k]
  __shared__ bf16 sP2[64 * 72];   // [64 kk][64 m (quarter)]
  __shared__ bf16 sH1[128 * 72];  // [128 rows][64 m (quarter)]
  __shared__ float sB1[256];
  __shared__ float sB2[64];

  const int tid = threadIdx.x;
  const int bt = blockIdx.x, r = blockIdx.y;
  const size_t b0 = (size_t)bt * 128;

  // stage X tile (rows b0..b0+127, cols r*64..r*64+63), fp32 -> bf16
  const float* xr = x + b0 * 4096 + r * 64;
#pragma unroll
  for (int i = 0; i < 8; ++i) {
    int idx = tid + i * 256;
    int row = idx >> 4, c4 = idx & 15;
    float4 v = *(const float4*)(xr + (size_t)row * 4096 + c4 * 4);
    *(bf16x4*)(&sX[row * 72 + c4 * 4]) = cvt4(v);
  }
  sB1[tid] = b1[r * 256 + tid];
  if (tid < 64) sB2[tid] = b2[r * 64 + tid];

  const float* p1r = p1 + (size_t)r * 16384;  // [256 m][64 k]
  const float* p2r = p2 + (size_t)r * 16384;  // [64 kk][256 m]

  const int w = tid >> 6, lane = tid & 63;
  const int q = lane >> 4, l16 = lane & 15;
  const int wm = w >> 1, wn = w & 1;  // wave quadrant: rows 64*wm, cols 32*wn

  const floatx4 fzero = {0.f, 0.f, 0.f, 0.f};
  floatx4 acc2[4][2];
#pragma unroll
  for (int mt = 0; mt < 4; ++mt)
#pragma unroll
    for (int nt = 0; nt < 2; ++nt) acc2[mt][nt] = fzero;

  for (int qh = 0; qh < 4; ++qh) {
    __syncthreads();  // protects sP1/sP2/sH1 re-staging vs previous quarter's reads
    // stage P1 quarter rows [qh*64, qh*64+64), P2 cols [qh*64, qh*64+64)
#pragma unroll
    for (int i = 0; i < 4; ++i) {
      int idx = tid + i * 256;
      int row = idx >> 4, c4 = idx & 15;
      float4 v = *(const float4*)(p1r + (size_t)(qh * 64 + row) * 64 + c4 * 4);
      *(bf16x4*)(&sP1[row * 72 + c4 * 4]) = cvt4(v);
      float4 u = *(const float4*)(p2r + (size_t)row * 256 + qh * 64 + c4 * 4);
      *(bf16x4*)(&sP2[row * 72 + c4 * 4]) = cvt4(u);
    }
    __syncthreads();

    // GEMM1: [128 x 64quarter], K=64 (2 ksteps)
    floatx4 acc1[4][2];
#pragma unroll
    for (int mt = 0; mt < 4; ++mt)
#pragma unroll
      for (int nt = 0; nt < 2; ++nt) acc1[mt][nt] = fzero;
#pragma unroll
    for (int ks = 0; ks < 2; ++ks) {
      bf16x8 a[4], bb[2];
#pragma unroll
      for (int mt = 0; mt < 4; ++mt)
        a[mt] = *(const bf16x8*)(&sX[(64 * wm + mt * 16 + l16) * 72 + ks * 32 + q * 8]);
#pragma unroll
      for (int nt = 0; nt < 2; ++nt)
        bb[nt] = *(const bf16x8*)(&sP1[(32 * wn + nt * 16 + l16) * 72 + ks * 32 + q * 8]);
#pragma unroll
      for (int mt = 0; mt < 4; ++mt)
#pragma unroll
        for (int nt = 0; nt < 2; ++nt) acc1[mt][nt] = MFMA(a[mt], bb[nt], acc1[mt][nt]);
    }
    // bias1 + ReLU -> bf16 -> sH1
#pragma unroll
    for (int mt = 0; mt < 4; ++mt) {
#pragma unroll
      for (int nt = 0; nt < 2; ++nt) {
        int c = 32 * wn + nt * 16 + l16;
        float bias1v = sB1[qh * 64 + c];
#pragma unroll
        for (int v = 0; v < 4; ++v) {
          int row = 64 * wm + mt * 16 + q * 4 + v;
          sH1[row * 72 + c] = (bf16)fmaxf(acc1[mt][nt][v] + bias1v, 0.f);
        }
      }
    }
    __syncthreads();
    // GEMM2 partial: K over this quarter's 64 m values (2 ksteps)
#pragma unroll
    for (int ks = 0; ks < 2; ++ks) {
      bf16x8 a2[4], bb2[2];
#pragma unroll
      for (int mt = 0; mt < 4; ++mt)
        a2[mt] = *(const bf16x8*)(&sH1[(64 * wm + mt * 16 + l16) * 72 + ks * 32 + q * 8]);
#pragma unroll
      for (int nt = 0; nt < 2; ++nt)
        bb2[nt] = *(const bf16x8*)(&sP2[(32 * wn + nt * 16 + l16) * 72 + ks * 32 + q * 8]);
#pragma unroll
      for (int mt = 0; mt < 4; ++mt)
#pragma unroll
        for (int nt = 0; nt < 2; ++nt) acc2[mt][nt] = MFMA(a2[mt], bb2[nt], acc2[mt][nt]);
    }
  }

  // epilogue: bias2 + ReLU -> bf16 -> global h2[b][r*64+kk]
  bf16* ho = h2 + b0 * 4096 + r * 64;
#pragma unroll
  for (int mt = 0; mt < 4; ++mt) {
#pragma unroll
    for (int nt = 0; nt < 2; ++nt) {
      int kk = 32 * wn + nt * 16 + l16;
      float b2v = sB2[kk];
#pragma unroll
      for (int v = 0; v < 4; ++v) {
        int row = 64 * wm + mt * 16 + q * 4 + v;
        ho[(size_t)row * 4096 + kk] = (bf16)fmaxf(acc2[mt][nt][v] + b2v, 0.f);
      }
    }
  }
}

// ---------------- Kernel 3: LayerNorm (in place, bf16) ----------------
__global__ __launch_bounds__(256) void ln_kernel(bf16* __restrict__ h,
                                                 const float* __restrict__ gamma,
                                                 const float* __restrict__ beta) {
  const int row = blockIdx.x;
  const int tid = threadIdx.x;
  bf16* hr = h + (size_t)row * 4096;
  float vals[16];
  float s = 0.f, ss = 0.f;
#pragma unroll
  for (int i = 0; i < 2; ++i) {
    bf16x8 v = *(const bf16x8*)(hr + (size_t)(i * 256 + tid) * 8);
#pragma unroll
    for (int j = 0; j < 8; ++j) {
      float f = (float)v[j];
      vals[i * 8 + j] = f;
      s += f;
      ss += f * f;
    }
  }
#pragma unroll
  for (int off = 32; off > 0; off >>= 1) {
    s += __shfl_down(s, off, 64);
    ss += __shfl_down(ss, off, 64);
  }
  __shared__ float red[8];
  const int w = tid >> 6, lane = tid & 63;
  if (lane == 0) { red[w] = s; red[4 + w] = ss; }
  __syncthreads();
  s = red[0] + red[1] + red[2] + red[3];
  ss = red[4] + red[5] + red[6] + red[7];
  const float mu = s * (1.f / 4096.f);
  const float var = ss * (1.f / 4096.f) - mu * mu;
  const float rsig = rsqrtf(var + 1e-5f);
#pragma unroll
  for (int i = 0; i < 2; ++i) {
    const int base = (i * 256 + tid) * 8;
    float4 g0 = *(const float4*)(gamma + base);
    float4 g1 = *(const float4*)(gamma + base + 4);
    float4 be0 = *(const float4*)(beta + base);
    float4 be1 = *(const float4*)(beta + base + 4);
    float g[8] = {g0.x, g0.y, g0.z, g0.w, g1.x, g1.y, g1.z, g1.w};
    float bb[8] = {be0.x, be0.y, be0.z, be0.w, be1.x, be1.y, be1.z, be1.w};
    bf16x8 o;
#pragma unroll
    for (int j = 0; j < 8; ++j) o[j] = (bf16)((vals[i * 8 + j] - mu) * rsig * g[j] + bb[j]);
    *(bf16x8*)(hr + base) = o;
  }
}

// ---------------- Kernel 4: out = relu(h_ln @ W^T + b) + x ----------------
// m97 structure: 128x128 tile, BK=32, 4 waves each 64x64 (4x4 MFMA tiles),
// global_load_lds width 16, both operands K-contiguous.
__global__ __launch_bounds__(256) void gemm_kernel(
    const bf16* __restrict__ A,   // h_ln [rows][4096] bf16 (chunk-local)
    const bf16* __restrict__ B,   // W    [4096][4096] bf16 (row j, K contiguous)
    const float* __restrict__ bias, const float* __restrict__ xres,
    float* __restrict__ out) {
  __shared__ bf16 sA[128 * 32];
  __shared__ bf16 sB[128 * 32];
  const int tid = threadIdx.x;
  const int n0 = blockIdx.x * 128;
  const int m0 = blockIdx.y * 128;
  const int w = tid >> 6, lane = tid & 63;
  const int q = lane >> 4, l16 = lane & 15;
  const int wm = w >> 1, wn = w & 1;

  const floatx4 fzero = {0.f, 0.f, 0.f, 0.f};
  floatx4 acc[4][4];
#pragma unroll
  for (int mt = 0; mt < 4; ++mt)
#pragma unroll
    for (int nt = 0; nt < 4; ++nt) acc[mt][nt] = fzero;

  const int ra = tid >> 2;           // 0..63: row within 64-row staging batch
  const int koff = (tid & 3) * 8;    // 0,8,16,24
  const bf16* aptr = A + (size_t)(m0 + ra) * 4096 + koff;
  const bf16* bptr = B + (size_t)(n0 + ra) * 4096 + koff;
  bf16* la = sA + tid * 8;  // byte offset tid*16: wave-uniform base + lane*16
  bf16* lb = sB + tid * 8;

  for (int k0 = 0; k0 < 4096; k0 += 32) {
    gl2lds16(aptr, la);
    gl2lds16(aptr + (size_t)64 * 4096, sA + 2048 + tid * 8);
    gl2lds16(bptr, lb);
    gl2lds16(bptr + (size_t)64 * 4096, sB + 2048 + tid * 8);
    aptr += 32;
    bptr += 32;
    __syncthreads();  // compiler emits vmcnt(0) drain here (m97 structure)
    bf16x8 af[4], bfr[4];
#pragma unroll
    for (int mt = 0; mt < 4; ++mt)
      af[mt] = *(const bf16x8*)(&sA[(64 * wm + mt * 16 + l16) * 32 + q * 8]);
#pragma unroll
    for (int nt = 0; nt < 4; ++nt)
      bfr[nt] = *(const bf16x8*)(&sB[(64 * wn + nt * 16 + l16) * 32 + q * 8]);
#pragma unroll
    for (int mt = 0; mt < 4; ++mt)
#pragma unroll
      for (int nt = 0; nt < 4; ++nt) acc[mt][nt] = MFMA(af[mt], bfr[nt], acc[mt][nt]);
    __syncthreads();
  }

  // epilogue: bias + ReLU + residual, fp32 store
#pragma unroll
  for (int nt = 0; nt < 4; ++nt) {
    const int col = n0 + 64 * wn + nt * 16 + l16;
    const float bv = bias[col];
#pragma unroll
    for (int mt = 0; mt < 4; ++mt) {
#pragma unroll
      for (int v = 0; v < 4; ++v) {
        const int row = m0 + 64 * wm + mt * 16 + q * 4 + v;
        const size_t o = (size_t)row * 4096 + col;
        out[o] = fmaxf(acc[mt][nt][v] + bv, 0.f) + xres[o];
      }
    }
  }
}

extern "C" void kernel_launch(void* const* d_in, const int* in_sizes, int n_in,
                              void* d_out, int out_size, void* d_ws, size_t ws_size,
                              hipStream_t stream) {
  const float* x = (const float*)d_in[0];
  const float* p1 = (const float*)d_in[1];
  const float* b1 = (const float*)d_in[2];
  const float* p2 = (const float*)d_in[3];
  const float* b2 = (const float*)d_in[4];
  const float* gamma = (const float*)d_in[5];
  const float* beta = (const float*)d_in[6];
  const float* W = (const float*)d_in[7];
  const float* bias = (const float*)d_in[8];
  float* out = (float*)d_out;

  // Workspace layout: [0, 32MB) W bf16; [32MB, 32MB + 64MB/nch) h bf16 chunk.
  // IMPORTANT: never assume ws_size >= 96MB. Chunk the batch so the h buffer
  // fits in (ws_size - 32MB). nch depends only on ws_size -> identical work
  // on every call (graph-capture safe, workspace-poison safe).
  const size_t WB_BYTES = (size_t)4096 * 4096 * 2;  // 32 MB
  const size_t H_BYTES = (size_t)8192 * 4096 * 2;   // 64 MB (full batch)
  bf16* Wb = (bf16*)d_ws;
  bf16* h = (bf16*)((char*)d_ws + WB_BYTES);

  size_t avail = ws_size > WB_BYTES ? ws_size - WB_BYTES : 0;
  int nch = 1;
  while (nch < 64 && H_BYTES / (size_t)nch > avail) nch <<= 1;
  const int rows = 8192 / nch;  // multiple of 128 for all grids

  cast_w_kernel<<<2048, 256, 0, stream>>>(W, Wb, 4096 * 4096 / 4);
  for (int c = 0; c < nch; ++c) {
    const float* xc = x + (size_t)c * rows * 4096;
    float* outc = out + (size_t)c * rows * 4096;
    blockdiag_kernel<<<dim3(rows / 128, 64), 256, 0, stream>>>(xc, p1, b1, p2, b2, h);
    ln_kernel<<<rows, 256, 0, stream>>>(h, gamma, beta);
    gemm_kernel<<<dim3(32, rows / 128), 256, 0, stream>>>(h, Wb, bias, xc, outc);
  }
}